// Round 1
// baseline (1382.833 us; speedup 1.0000x reference)
//
#include <hip/hip_runtime.h>

#define N_NODES 20000
#define N_EDGES 8192
#define DIM 128
#define NW 313   // ceil(N_NODES/64)
#define EW 128   // N_EDGES/64

typedef unsigned long long u64;

// ---------------------------------------------------------------------------
// K1: stream H once -> natural bitmask [n][EW words], transposed bitmask
//     [NW words][e], Dv (row popcounts), De (col popcounts).
// grid (32, 313), block 256 (4 waves). Wave covers 64 consecutive e.
// ---------------------------------------------------------------------------
__global__ __launch_bounds__(256) void k1_mask(const float* __restrict__ H,
                                               u64* __restrict__ maskN,
                                               u64* __restrict__ maskT,
                                               float* __restrict__ Dv,
                                               float* __restrict__ De) {
  __shared__ int dcnt[4][64];
  const int tid  = threadIdx.x;
  const int wave = tid >> 6, lane = tid & 63;
  const int e  = blockIdx.x * 256 + wave * 64 + lane;
  const int n0 = blockIdx.y * 64;

  u64 tmask = 0;
  for (int i = 0; i < 64; ++i) {
    const int n = n0 + i;
    bool pred = false;
    if (n < N_NODES) pred = (H[(size_t)n * N_EDGES + e] != 0.0f);
    const u64 bal = __ballot(pred);
    if (lane == 0) {
      dcnt[wave][i] = (n < N_NODES) ? __popcll(bal) : 0;
      if (n < N_NODES) maskN[(size_t)n * EW + blockIdx.x * 4 + wave] = bal;
    }
    tmask |= pred ? (1ull << i) : 0ull;
  }
  maskT[(size_t)blockIdx.y * N_EDGES + e] = tmask;
  atomicAdd(&De[e], (float)__popcll(tmask));   // integer-valued: deterministic

  __syncthreads();
  if (tid < 64 && (n0 + tid) < N_NODES) {
    atomicAdd(&Dv[n0 + tid],
              (float)(dcnt[0][tid] + dcnt[1][tid] + dcnt[2][tid] + dcnt[3][tid]));
  }
}

// ---------------------------------------------------------------------------
// K2: M[e][d] = De_inv[e] * sum_{n in col e} X[n][d]
// One wave per e (4 e / block). Lane covers 2 dims (float2).
// Transposed mask scanned with word-prefetch; X loads rotated 2-deep.
// ---------------------------------------------------------------------------
__global__ __launch_bounds__(256) void k2_edge(const float* __restrict__ X,
                                               const u64* __restrict__ maskT,
                                               const float* __restrict__ De,
                                               float* __restrict__ M) {
  const int wave = threadIdx.x >> 6, lane = threadIdx.x & 63;
  const int e  = blockIdx.x * 4 + wave;
  const int d0 = lane * 2;

  float accx = 0.f, accy = 0.f;
  int c = 0;
  u64 w  = maskT[e];                       // word c=0
  u64 wn = maskT[(size_t)N_EDGES + e];     // prefetched word c=1

  auto nextn = [&](int& n) -> bool {
    while (w == 0) {
      ++c;
      if (c >= NW) return false;
      w  = wn;
      wn = (c + 1 < NW) ? maskT[(size_t)(c + 1) * N_EDGES + e] : 0ull;
    }
    const int bit = __builtin_ctzll(w);
    w &= (w - 1);
    n = c * 64 + bit;
    return true;
  };

  int n0;
  bool h0 = nextn(n0);
  float2 p0 = make_float2(0.f, 0.f);
  if (h0) p0 = *(const float2*)&X[(size_t)n0 * DIM + d0];
  while (h0) {
    int n1;
    const bool h1 = nextn(n1);
    float2 p1 = make_float2(0.f, 0.f);
    if (h1) p1 = *(const float2*)&X[(size_t)n1 * DIM + d0];  // issue before consuming p0
    accx += p0.x; accy += p0.y;
    p0 = p1; h0 = h1;
  }

  const float de = De[e];
  const float s  = (de != 0.f) ? (1.f / de) : 0.f;
  float2 o; o.x = accx * s; o.y = accy * s;
  *(float2*)&M[(size_t)e * DIM + d0] = o;
}

// ---------------------------------------------------------------------------
// K3: Y[n][d] = Dv_inv[n] * sum_{e in row n} M[e][d]
// One wave per n (4 n / block). M is 4 MB -> L2 resident.
// ---------------------------------------------------------------------------
__global__ __launch_bounds__(256) void k3_node(const float* __restrict__ M,
                                               const u64* __restrict__ maskN,
                                               const float* __restrict__ Dv,
                                               float* __restrict__ Y) {
  const int wave = threadIdx.x >> 6, lane = threadIdx.x & 63;
  const int n  = blockIdx.x * 4 + wave;   // 5000*4 == 20000 exactly
  const int d0 = lane * 2;

  float accx = 0.f, accy = 0.f;
  int c = 0;
  const u64* row = maskN + (size_t)n * EW;
  u64 w  = row[0];
  u64 wn = row[1];

  auto nexte = [&](int& eo) -> bool {
    while (w == 0) {
      ++c;
      if (c >= EW) return false;
      w  = wn;
      wn = (c + 1 < EW) ? row[c + 1] : 0ull;
    }
    const int bit = __builtin_ctzll(w);
    w &= (w - 1);
    eo = c * 64 + bit;
    return true;
  };

  int e0;
  bool h0 = nexte(e0);
  float2 p0 = make_float2(0.f, 0.f);
  if (h0) p0 = *(const float2*)&M[(size_t)e0 * DIM + d0];
  while (h0) {
    int e1;
    const bool h1 = nexte(e1);
    float2 p1 = make_float2(0.f, 0.f);
    if (h1) p1 = *(const float2*)&M[(size_t)e1 * DIM + d0];
    accx += p0.x; accy += p0.y;
    p0 = p1; h0 = h1;
  }

  const float dv = Dv[n];
  const float s  = (dv != 0.f) ? (1.f / dv) : 0.f;
  float2 o; o.x = accx * s; o.y = accy * s;
  *(float2*)&Y[(size_t)n * DIM + d0] = o;
}

// ---------------------------------------------------------------------------
// K4: out[n][o] = sum_d Y[n][d] * W[o][d] + b[o]
// W transposed into LDS with +1 padding (conflict-free read & write).
// ---------------------------------------------------------------------------
#define TILE_N 64
__global__ __launch_bounds__(256) void k4_out(const float* __restrict__ Y,
                                              const float* __restrict__ W,
                                              const float* __restrict__ b,
                                              float* __restrict__ out) {
  __shared__ float Wl[DIM][DIM + 1];   // Wl[d][o] = W[o][d]
  __shared__ float Yl[TILE_N][DIM];
  const int t  = threadIdx.x;
  const int n0 = blockIdx.x * TILE_N;

  {
    const int d = t & 127, oh = t >> 7;
    for (int k = 0; k < 64; ++k) {
      const int o = k * 2 + oh;
      Wl[d][o] = W[o * DIM + d];   // coalesced read, bank-stride-1 write
    }
  }
  for (int r = 0; r < TILE_N * DIM / 256; ++r) {
    const int flat = r * 256 + t;
    const int nl = flat >> 7, d = flat & 127;
    const int n = n0 + nl;
    Yl[nl][d] = (n < N_NODES) ? Y[(size_t)n * DIM + d] : 0.f;
  }
  __syncthreads();

  const int o = t & 127;
  const float bias = b[o];
  for (int r = 0; r < TILE_N / 2; ++r) {
    const int nl = r * 2 + (t >> 7);
    const int n  = n0 + nl;
    float f = bias;
#pragma unroll 8
    for (int d = 0; d < DIM; ++d) f += Yl[nl][d] * Wl[d][o];
    if (n < N_NODES) out[(size_t)n * DIM + o] = f;
  }
}

// ---------------------------------------------------------------------------
extern "C" void kernel_launch(void* const* d_in, const int* in_sizes, int n_in,
                              void* d_out, int out_size, void* d_ws, size_t ws_size,
                              hipStream_t stream) {
  const float* X = (const float*)d_in[0];
  const float* H = (const float*)d_in[1];
  const float* W = (const float*)d_in[2];
  const float* b = (const float*)d_in[3];
  float* out = (float*)d_out;

  char* ws = (char*)d_ws;
  // workspace carve (all 8B aligned), total ~53 MB
  u64*   maskN = (u64*)(ws + 0);                     // 20,480,000 B
  u64*   maskT = (u64*)(ws + 20480000);              // 20,512,768 B
  float* M     = (float*)(ws + 40992768);            //  4,194,304 B
  float* Dv    = (float*)(ws + 45187072);            //     80,000 B
  float* De    = (float*)(ws + 45267072);            //     32,768 B
  float* Y     = (float*)(ws + 45299840);            // 10,240,000 B

  // zero the degree accumulators (Dv and De are contiguous)
  hipMemsetAsync(Dv, 0, 80000 + 32768, stream);

  k1_mask<<<dim3(32, 313), 256, 0, stream>>>(H, maskN, maskT, Dv, De);
  k2_edge<<<N_EDGES / 4, 256, 0, stream>>>(X, maskT, De, M);
  k3_node<<<N_NODES / 4, 256, 0, stream>>>(M, maskN, Dv, Y);
  k4_out<<<(N_NODES + TILE_N - 1) / TILE_N, 256, 0, stream>>>(Y, W, b, out);
}

// Round 2
// 614.850 us; speedup vs baseline: 2.2491x; 2.2491x over previous
//
#include <hip/hip_runtime.h>

#define N_NODES 20000
#define N_EDGES 8192
#define DIM 128
#define NWORDS 313        // ceil(20000/64) node-words
#define XT_STRIDE 20032   // NWORDS*64, padded node dim for Xt
#define NT_STRIDE 20096   // maskNT row length in u64 (>= 209*96 = 20064), zero-padded
#define KSPLIT 4
#define WPC 80            // mask words per K-chunk in k2m (80,80,80,73)

typedef unsigned long long u64;
typedef __attribute__((ext_vector_type(8))) __bf16 bf16x8_t;
typedef __attribute__((ext_vector_type(4))) float f32x4;

__device__ __forceinline__ f32x4 mfma16(bf16x8_t a, bf16x8_t b, f32x4 c) {
  return __builtin_amdgcn_mfma_f32_16x16x32_bf16(a, b, c, 0, 0, 0);
}

// fp32 -> bf16 bits, round-to-nearest-even
__device__ __forceinline__ ushort f2bf(float f) {
  unsigned int x = __float_as_uint(f);
  unsigned int r = (x + 0x7FFFu + ((x >> 16) & 1u)) >> 16;
  return (ushort)r;
}

// expand 8 mask bits -> 8 bf16 values (1.0f / 0.0f), packed pairs
__device__ __forceinline__ bf16x8_t expand8(unsigned int byte) {
  union { unsigned int u[4]; bf16x8_t v; } A;
#pragma unroll
  for (int p = 0; p < 4; ++p) {
    unsigned int tt = (byte >> (2 * p)) & 3u;
    A.u[p] = ((tt | (tt << 15)) & 0x00010001u) * 0x3F80u;
  }
  return A.v;
}

#define GLOAD_LDS16(g, l)                                                  \
  __builtin_amdgcn_global_load_lds(                                        \
      (const __attribute__((address_space(1))) void*)(g),                  \
      (__attribute__((address_space(3))) void*)(l), 16, 0, 0)

// ---------------------------------------------------------------------------
// K0: Xt[d][n] = bf16(X[n][d]), n padded to XT_STRIDE with zeros.
// ---------------------------------------------------------------------------
__global__ __launch_bounds__(256) void k0_xt(const float* __restrict__ X,
                                             ushort* __restrict__ Xt) {
  __shared__ float T[64][129];
  const int t = threadIdx.x;
  const int n0 = blockIdx.x * 64;
#pragma unroll
  for (int i = 0; i < 32; ++i) {
    const int flat = i * 256 + t;
    const int nl = flat >> 7, d = flat & 127;
    const int n = n0 + nl;
    T[nl][d] = (n < N_NODES) ? X[(size_t)n * DIM + d] : 0.f;
  }
  __syncthreads();
  const int d = t >> 1, half = t & 1;
#pragma unroll
  for (int g = 0; g < 4; ++g) {
    union { ushort h[8]; int4 v; } u;
#pragma unroll
    for (int j = 0; j < 8; ++j) {
      const int nl = half * 32 + g * 8 + j;
      u.h[j] = f2bf(T[nl][d]);
    }
    *(int4*)&Xt[(size_t)d * XT_STRIDE + n0 + half * 32 + g * 8] = u.v;
  }
}

// ---------------------------------------------------------------------------
// K1: stream H once -> maskT[c][e] (bits = nodes), maskNT[ew][n] (bits = edges),
//     Dv, De. grid (32, 313), block 256.
// ---------------------------------------------------------------------------
__global__ __launch_bounds__(256) void k1_mask(const float* __restrict__ H,
                                               u64* __restrict__ maskNT,
                                               u64* __restrict__ maskT,
                                               float* __restrict__ Dv,
                                               float* __restrict__ De) {
  __shared__ int dcnt[4][64];
  const int tid  = threadIdx.x;
  const int wave = tid >> 6, lane = tid & 63;
  const int e  = blockIdx.x * 256 + wave * 64 + lane;
  const int n0 = blockIdx.y * 64;
  const int ew = blockIdx.x * 4 + wave;   // edge-window index 0..127

  u64 tmask = 0;
  for (int i = 0; i < 64; ++i) {
    const int n = n0 + i;
    bool pred = false;
    if (n < N_NODES) pred = (H[(size_t)n * N_EDGES + e] != 0.0f);
    const u64 bal = __ballot(pred);
    if (lane == 0) {
      dcnt[wave][i] = (n < N_NODES) ? __popcll(bal) : 0;
      maskNT[(size_t)ew * NT_STRIDE + n] = bal;   // n <= 20031 < NT_STRIDE
    }
    tmask |= pred ? (1ull << i) : 0ull;
  }
  maskT[(size_t)blockIdx.y * N_EDGES + e] = tmask;
  atomicAdd(&De[e], (float)__popcll(tmask));   // integer-valued: deterministic

  __syncthreads();
  if (tid < 64 && (n0 + tid) < N_NODES) {
    atomicAdd(&Dv[n0 + tid],
              (float)(dcnt[0][tid] + dcnt[1][tid] + dcnt[2][tid] + dcnt[3][tid]));
  }
}

// ---------------------------------------------------------------------------
// K2m: Mp[p][e][d] partial of (H^T X). 256 blocks = 64 e-tiles x 4 K-chunks.
// 4 waves (2x2), wave tile 64x64, BK=64 (one mask word), MFMA 16x16x32 bf16.
// ---------------------------------------------------------------------------
__global__ __launch_bounds__(256) void k2m(const u64* __restrict__ maskT,
                                           const ushort* __restrict__ Xt,
                                           float* __restrict__ Mp) {
  __shared__ __align__(16) char lds[2][16384];
  const int t = threadIdx.x, lane = t & 63, w = t >> 6;
  const int wr = w >> 1, wc = w & 1;
  const int bid = blockIdx.x;
  const int p  = bid >> 6;
  const int eb = (bid & 63) * 128;
  const int w0 = p * WPC;
  const int nsteps = min(WPC, NWORDS - w0);
  const int l15 = lane & 15, lh = lane >> 4;

  f32x4 acc[4][4];
#pragma unroll
  for (int m = 0; m < 4; ++m)
#pragma unroll
    for (int n = 0; n < 4; ++n) acc[m][n] = (f32x4){0.f, 0.f, 0.f, 0.f};

  auto stage = [&](int buf, int ks) {
#pragma unroll
    for (int i = 0; i < 4; ++i) {
      const int flat = i * 256 + t;
      const int d = flat >> 3, sp = flat & 7;
      const int s = sp ^ (d & 7);                 // inverse-swizzled source
      const ushort* src = Xt + (size_t)d * XT_STRIDE + (w0 + ks) * 64 + s * 8;
      GLOAD_LDS16(src, &lds[buf][(i * 256 + w * 64) * 16]);
    }
  };
  auto loadwords = [&](u64* wd, int ks) {
#pragma unroll
    for (int m = 0; m < 4; ++m)
      wd[m] = maskT[(size_t)(w0 + ks) * N_EDGES + eb + wr * 64 + m * 16 + l15];
  };

  u64 wcur[4], wnxt[4];
  stage(0, 0);
  loadwords(wcur, 0);
  __syncthreads();

  int buf = 0;
  for (int ks = 0; ks < nsteps; ++ks) {
    const bool pre = (ks + 1 < nsteps);
    if (pre) { stage(buf ^ 1, ks + 1); loadwords(wnxt, ks + 1); }

    bf16x8_t bf[2][4];
#pragma unroll
    for (int kh = 0; kh < 2; ++kh)
#pragma unroll
      for (int fn = 0; fn < 4; ++fn) {
        const int c = wc * 64 + fn * 16 + l15;
        const int s = kh * 4 + lh;
        const int slot = 8 * c + (s ^ (c & 7));   // swizzled read
        bf[kh][fn] = *(const bf16x8_t*)&lds[buf][slot * 16];
      }
#pragma unroll
    for (int m = 0; m < 4; ++m) {
#pragma unroll
      for (int kh = 0; kh < 2; ++kh) {
        const unsigned int half = (unsigned int)(wcur[m] >> (kh * 32));
        const unsigned int byte = (half >> (lh * 8)) & 0xFFu;
        const bf16x8_t a = expand8(byte);
#pragma unroll
        for (int fn = 0; fn < 4; ++fn)
          acc[m][fn] = mfma16(a, bf[kh][fn], acc[m][fn]);
      }
    }
    __syncthreads();
    if (pre) {
#pragma unroll
      for (int m = 0; m < 4; ++m) wcur[m] = wnxt[m];
      buf ^= 1;
    }
  }

#pragma unroll
  for (int m = 0; m < 4; ++m)
#pragma unroll
    for (int fn = 0; fn < 4; ++fn)
#pragma unroll
      for (int r = 0; r < 4; ++r) {
        const int e = eb + wr * 64 + m * 16 + lh * 4 + r;
        const int d = wc * 64 + fn * 16 + l15;
        Mp[((size_t)p * N_EDGES + e) * DIM + d] = acc[m][fn][r];
      }
}

// ---------------------------------------------------------------------------
// K2r: Mt[d][e] = bf16( (sum_p Mp[p][e][d]) * De_inv[e] ).  256 blocks x 32 e.
// ---------------------------------------------------------------------------
__global__ __launch_bounds__(256) void k2r(const float* __restrict__ Mp,
                                           const float* __restrict__ De,
                                           ushort* __restrict__ Mt) {
  __shared__ float T[32][129];
  const int t = threadIdx.x;
  const int eb = blockIdx.x * 32;
#pragma unroll
  for (int i = 0; i < 16; ++i) {
    const int flat = i * 256 + t;
    const int el = flat >> 7, d = flat & 127;
    const int e = eb + el;
    float s = 0.f;
#pragma unroll
    for (int p = 0; p < KSPLIT; ++p) s += Mp[((size_t)p * N_EDGES + e) * DIM + d];
    const float de = De[e];
    T[el][d] = s * ((de != 0.f) ? 1.f / de : 0.f);
  }
  __syncthreads();
#pragma unroll
  for (int i = 0; i < 16; ++i) {
    const int flat = i * 256 + t;
    const int el = flat & 31, d = flat >> 5;
    Mt[(size_t)d * N_EDGES + eb + el] = f2bf(T[el][d]);
  }
}

// ---------------------------------------------------------------------------
// K3m: Y[n][d] = Dv_inv[n] * (H M)[n][d]. 209 blocks, BM=96 (wave tile 48x64).
// ---------------------------------------------------------------------------
__global__ __launch_bounds__(256) void k3m(const u64* __restrict__ maskNT,
                                           const ushort* __restrict__ Mt,
                                           const float* __restrict__ Dv,
                                           float* __restrict__ Y) {
  __shared__ __align__(16) char lds[2][16384];
  const int t = threadIdx.x, lane = t & 63, w = t >> 6;
  const int wr = w >> 1, wc = w & 1;
  const int nb = blockIdx.x * 96;
  const int l15 = lane & 15, lh = lane >> 4;

  f32x4 acc[3][4];
#pragma unroll
  for (int m = 0; m < 3; ++m)
#pragma unroll
    for (int n = 0; n < 4; ++n) acc[m][n] = (f32x4){0.f, 0.f, 0.f, 0.f};

  auto stage = [&](int buf, int ks) {
#pragma unroll
    for (int i = 0; i < 4; ++i) {
      const int flat = i * 256 + t;
      const int d = flat >> 3, sp = flat & 7;
      const int s = sp ^ (d & 7);
      const ushort* src = Mt + (size_t)d * N_EDGES + ks * 64 + s * 8;
      GLOAD_LDS16(src, &lds[buf][(i * 256 + w * 64) * 16]);
    }
  };
  auto loadwords = [&](u64* wd, int ks) {
#pragma unroll
    for (int m = 0; m < 3; ++m)
      wd[m] = maskNT[(size_t)ks * NT_STRIDE + nb + wr * 48 + m * 16 + l15];
  };

  u64 wcur[3], wnxt[3];
  stage(0, 0);
  loadwords(wcur, 0);
  __syncthreads();

  int buf = 0;
  for (int ks = 0; ks < 128; ++ks) {
    const bool pre = (ks + 1 < 128);
    if (pre) { stage(buf ^ 1, ks + 1); loadwords(wnxt, ks + 1); }

    bf16x8_t bf[2][4];
#pragma unroll
    for (int kh = 0; kh < 2; ++kh)
#pragma unroll
      for (int fn = 0; fn < 4; ++fn) {
        const int c = wc * 64 + fn * 16 + l15;
        const int s = kh * 4 + lh;
        const int slot = 8 * c + (s ^ (c & 7));
        bf[kh][fn] = *(const bf16x8_t*)&lds[buf][slot * 16];
      }
#pragma unroll
    for (int m = 0; m < 3; ++m) {
#pragma unroll
      for (int kh = 0; kh < 2; ++kh) {
        const unsigned int half = (unsigned int)(wcur[m] >> (kh * 32));
        const unsigned int byte = (half >> (lh * 8)) & 0xFFu;
        const bf16x8_t a = expand8(byte);
#pragma unroll
        for (int fn = 0; fn < 4; ++fn)
          acc[m][fn] = mfma16(a, bf[kh][fn], acc[m][fn]);
      }
    }
    __syncthreads();
    if (pre) {
#pragma unroll
      for (int m = 0; m < 3; ++m) wcur[m] = wnxt[m];
      buf ^= 1;
    }
  }

#pragma unroll
  for (int m = 0; m < 3; ++m)
#pragma unroll
    for (int fn = 0; fn < 4; ++fn)
#pragma unroll
      for (int r = 0; r < 4; ++r) {
        const int n = nb + wr * 48 + m * 16 + lh * 4 + r;
        if (n < N_NODES) {
          const float dv = Dv[n];
          const float sc = (dv != 0.f) ? 1.f / dv : 0.f;
          Y[(size_t)n * DIM + wc * 64 + fn * 16 + l15] = acc[m][fn][r] * sc;
        }
      }
}

// ---------------------------------------------------------------------------
// K4: out[n][o] = sum_d Y[n][d] * W[o][d] + b[o]  (in-place on d_out)
// ---------------------------------------------------------------------------
#define TILE_N 64
__global__ __launch_bounds__(256) void k4_out(const float* Y,
                                              const float* __restrict__ W,
                                              const float* __restrict__ b,
                                              float* out) {
  __shared__ float Wl[DIM][DIM + 1];   // Wl[d][o] = W[o][d]
  __shared__ float Yl[TILE_N][DIM];
  const int t  = threadIdx.x;
  const int n0 = blockIdx.x * TILE_N;

  {
    const int d = t & 127, oh = t >> 7;
    for (int k = 0; k < 64; ++k) {
      const int o = k * 2 + oh;
      Wl[d][o] = W[o * DIM + d];
    }
  }
  for (int r = 0; r < TILE_N * DIM / 256; ++r) {
    const int flat = r * 256 + t;
    const int nl = flat >> 7, d = flat & 127;
    const int n = n0 + nl;
    Yl[nl][d] = (n < N_NODES) ? Y[(size_t)n * DIM + d] : 0.f;
  }
  __syncthreads();

  const int o = t & 127;
  const float bias = b[o];
  for (int r = 0; r < TILE_N / 2; ++r) {
    const int nl = r * 2 + (t >> 7);
    const int n  = n0 + nl;
    float f = bias;
#pragma unroll 8
    for (int d = 0; d < DIM; ++d) f += Yl[nl][d] * Wl[d][o];
    if (n < N_NODES) out[(size_t)n * DIM + o] = f;
  }
}

// ---------------------------------------------------------------------------
extern "C" void kernel_launch(void* const* d_in, const int* in_sizes, int n_in,
                              void* d_out, int out_size, void* d_ws, size_t ws_size,
                              hipStream_t stream) {
  const float* X = (const float*)d_in[0];
  const float* H = (const float*)d_in[1];
  const float* W = (const float*)d_in[2];
  const float* b = (const float*)d_in[3];
  float* out = (float*)d_out;

  char* ws = (char*)d_ws;
  u64*    maskT  = (u64*)(ws + 0);            // 313*8192*8      = 20,512,768
  u64*    maskNT = (u64*)(ws + 20512768);     // 128*20096*8     = 20,578,304
  ushort* Xt     = (ushort*)(ws + 41091072);  // 128*20032*2     =  5,128,192
  float*  Mp     = (float*)(ws + 46219264);   // 4*8192*128*4    = 16,777,216
  ushort* Mt     = (ushort*)(ws + 62996480);  // 128*8192*2      =  2,097,152
  float*  Dv     = (float*)(ws + 65093632);   // 80,000
  float*  De     = (float*)(ws + 65173632);   // 32,768  (end ~65.2 MB)

  hipMemsetAsync(maskNT, 0, 20578304, stream);      // incl. zero padding rows
  hipMemsetAsync(Dv, 0, 80000 + 32768, stream);

  k0_xt  <<<313, 256, 0, stream>>>(X, Xt);
  k1_mask<<<dim3(32, 313), 256, 0, stream>>>(H, maskNT, maskT, Dv, De);
  k2m    <<<256, 256, 0, stream>>>(maskT, Xt, Mp);
  k2r    <<<256, 256, 0, stream>>>(Mp, De, Mt);
  k3m    <<<209, 256, 0, stream>>>(maskNT, Mt, Dv, out);
  k4_out <<<313, 256, 0, stream>>>(out, W, b, out);
}